// Round 14
// baseline (278.091 us; speedup 1.0000x reference)
//
#include <hip/hip_runtime.h>
#include <hip/hip_bf16.h>

// ---------- types ----------
using short8  = __attribute__((ext_vector_type(8))) short;
using ushort8 = __attribute__((ext_vector_type(8))) unsigned short;
using f32x4   = __attribute__((ext_vector_type(4))) float;

#define GLB(p)  ((const __attribute__((address_space(1))) void*)(p))
#define LDSP(p) ((__attribute__((address_space(3))) void*)(p))

static __device__ __forceinline__ unsigned short f2bf(float f) {
    union { float f; unsigned u; } v; v.f = f;
    unsigned u = v.u;
    u += 0x7fffu + ((u >> 16) & 1u);   // round-to-nearest-even
    return (unsigned short)(u >> 16);
}

// ---------- problem constants ----------
#define K_DIM 2048
#define N_DIM 2048
#define M_TOTAL 26112
#define N_GROUPS 8

// ---------- kernel 1: merged convert, one launch (r12 verbatim) ----------
__global__ __launch_bounds__(256) void cvt_all(
        const float* __restrict__ A0, const float* __restrict__ A1,
        const float* __restrict__ A2, const float* __restrict__ A3,
        const float* __restrict__ A4, const float* __restrict__ A5,
        const float* __restrict__ A6, const float* __restrict__ A7,
        const float* __restrict__ B,
        unsigned short* __restrict__ Acat, unsigned short* __restrict__ Bt) {
    int b   = blockIdx.x;
    int tid = threadIdx.x;
    if (b < 4096) {
        __shared__ float t[32][33];
        int bx = b & 63, by = b >> 6;
        int tx = tid & 31, ty = tid >> 5;   // 32 x 8
#pragma unroll
        for (int i = 0; i < 32; i += 8)
            t[ty + i][tx] = B[(long)(by * 32 + ty + i) * N_DIM + bx * 32 + tx];
        __syncthreads();
#pragma unroll
        for (int i = 0; i < 32; i += 8)
            Bt[(long)(bx * 32 + ty + i) * K_DIM + by * 32 + tx] = f2bf(t[tx][ty + i]);
    } else {
        int ab = b - 4096;
        const float* src; int gb;   // group base (16-row units)
        if      (ab < 256)  { src = A0; gb = 0;    }
        else if (ab < 384)  { src = A1; gb = 256;  }
        else if (ab < 448)  { src = A2; gb = 384;  }
        else if (ab < 960)  { src = A3; gb = 448;  }
        else if (ab < 992)  { src = A4; gb = 960;  }
        else if (ab < 1184) { src = A5; gb = 992;  }
        else if (ab < 1568) { src = A6; gb = 1184; }
        else                { src = A7; gb = 1568; }
        const float* s    = src  + (long)(ab - gb) * 16 * K_DIM;
        unsigned short* d = Acat + (long)ab * 16 * K_DIM;
#pragma unroll 4
        for (int i = 0; i < 16; ++i) {
            long off = (long)i * K_DIM + tid * 8;
            float4 x = *(const float4*)(s + off);
            float4 y = *(const float4*)(s + off + 4);
            ushort8 o;
            o[0] = f2bf(x.x); o[1] = f2bf(x.y); o[2] = f2bf(x.z); o[3] = f2bf(x.w);
            o[4] = f2bf(y.x); o[5] = f2bf(y.y); o[6] = f2bf(y.z); o[7] = f2bf(y.w);
            *(ushort8*)(d + off) = o;
        }
    }
}

// ---------- kernel 2: 256x256 GEMM, 2 mega-phases / K-tile (2 barriers) ----------
// vs r13: ph1+ph2 merged into phA, ph3+ph4 into phB.  Region safety: every stage
// lands exactly 1 all-waves barrier after its region's consumption (A(T+2)h0
// moved to phB for this).  vmcnt ledger: uniform VMC(8) per phase — phA's drains
// phA(T-1) (A(T)h1 ready for phB's reads); phB's drains phB(T-1) (tile T+1 ready
// for phA(T+1)'s reads).  Every VMC precedes its dependent ds_reads by >=1 barrier.

#define PBAR() __builtin_amdgcn_s_barrier()
#define VMC_(n) asm volatile("s_waitcnt vmcnt(" #n ")" ::: "memory")
#define VMCX(n) VMC_(n)
#define VMC(n)  VMC_(n)

#define ST_A(BUF, H, L, TT)                                                        \
    __builtin_amdgcn_global_load_lds(                                              \
        GLB(aSt + (long)((H) * 128 + (L) * 64) * K_DIM + (TT) * 64),               \
        LDSP(lds + (BUF) * 32768 + (H) * 8192 + (L) * 4096 + w * 512), 16, 0, 0)
#define ST_B(BUF, H, L, TT)                                                        \
    __builtin_amdgcn_global_load_lds(                                              \
        GLB(bSt + (long)((H) * 128 + (L) * 64) * K_DIM + (TT) * 64),               \
        LDSP(lds + (BUF) * 32768 + 16384 + (H) * 8192 + (L) * 4096 + w * 512), 16, 0, 0)

#define MMQ(MH, NH, AV, BV)                                                        \
    _Pragma("unroll") for (int i = 0; i < 4; ++i)                                  \
    _Pragma("unroll") for (int j = 0; j < 2; ++j)                                  \
        acc[(MH) * 4 + i][(NH) * 2 + j] = __builtin_amdgcn_mfma_f32_16x16x32_bf16( \
            AV[i], BV[j], acc[(MH) * 4 + i][(NH) * 2 + j], 0, 0, 0);

// one K-tile = 2 mega-phases.  VA/VB are vmcnt literals (steady: 8,8).
#define TILE2(BUF, T, DO1, DO2, VA, VB)                                                 \
    do {                                                                                \
        const unsigned short* pA = lds + (BUF) * 32768 + wm * 1024 + r16 * 64;          \
        const unsigned short* pB = lds + (BUF) * 32768 + 16384 + wn * 1024 + r16 * 64;  \
        short8 a0[4], a1[4], b00[2], b01[2], b10[2], b11[2];                            \
        /* ---- phA: read A-h0 + B-h0 + B-h1; stage A(T+1)h1 -> buf^1; VMC; 32 MFMA */  \
        _Pragma("unroll") for (int i = 0; i < 4; ++i) {                                 \
            a0[i] = *(const short8*)(pA + i * 2048 + c0 * 8);                           \
            a1[i] = *(const short8*)(pA + i * 2048 + c1 * 8);                           \
        }                                                                               \
        _Pragma("unroll") for (int j = 0; j < 2; ++j) {                                 \
            b00[j] = *(const short8*)(pB + j * 4096 + c0 * 8);                          \
            b01[j] = *(const short8*)(pB + j * 4096 + c1 * 8);                          \
            b10[j] = *(const short8*)(pB + 8192 + j * 4096 + c0 * 8);                   \
            b11[j] = *(const short8*)(pB + 8192 + j * 4096 + c1 * 8);                   \
        }                                                                               \
        if (DO1) { ST_A((BUF) ^ 1, 1, 0, (T) + 1); ST_A((BUF) ^ 1, 1, 1, (T) + 1); }    \
        VMCX(VA);                                                                       \
        __builtin_amdgcn_s_setprio(1);                                                  \
        MMQ(0, 0, a0, b00); MMQ(0, 0, a1, b01);                                         \
        MMQ(0, 1, a0, b10); MMQ(0, 1, a1, b11);                                         \
        __builtin_amdgcn_s_setprio(0); PBAR();                                          \
        /* ---- phB: read A-h1; stage A(T+2)h0 + B(T+2)h0 + B(T+2)h1; VMC; 32 MFMA */   \
        _Pragma("unroll") for (int i = 0; i < 4; ++i) {                                 \
            a0[i] = *(const short8*)(pA + 8192 + i * 2048 + c0 * 8);                    \
            a1[i] = *(const short8*)(pA + 8192 + i * 2048 + c1 * 8);                    \
        }                                                                               \
        if (DO2) {                                                                      \
            ST_A((BUF), 0, 0, (T) + 2); ST_A((BUF), 0, 1, (T) + 2);                     \
            ST_B((BUF), 0, 0, (T) + 2); ST_B((BUF), 0, 1, (T) + 2);                     \
            ST_B((BUF), 1, 0, (T) + 2); ST_B((BUF), 1, 1, (T) + 2);                     \
        }                                                                               \
        VMCX(VB);                                                                       \
        __builtin_amdgcn_s_setprio(1);                                                  \
        MMQ(1, 0, a0, b00); MMQ(1, 0, a1, b01);                                         \
        MMQ(1, 1, a0, b10); MMQ(1, 1, a1, b11);                                         \
        __builtin_amdgcn_s_setprio(0);                                                  \
    } while (0)

// ---- 64-row quarter tile (tail), 2 mega-phases; 5 loads/tile all in phB ----
#define ST_A4(BUF, TT)                                                             \
    __builtin_amdgcn_global_load_lds(                                              \
        GLB(aSt + (long)(TT) * 64),                                                \
        LDSP(lds + (BUF) * 4096 + w * 512), 16, 0, 0)
#define ST_B4(BUF, H, L, TT)                                                       \
    __builtin_amdgcn_global_load_lds(                                              \
        GLB(bSt + (long)((H) * 128 + (L) * 64) * K_DIM + (TT) * 64),               \
        LDSP(lds + 8192 + (BUF) * 16384 + (H) * 8192 + (L) * 4096 + w * 512), 16, 0, 0)

#define MMQ4(NH, AV, BV)                                                           \
    _Pragma("unroll") for (int i = 0; i < 2; ++i)                                  \
    _Pragma("unroll") for (int j = 0; j < 2; ++j)                                  \
        acc[i][(NH) * 2 + j] = __builtin_amdgcn_mfma_f32_16x16x32_bf16(            \
            AV[i], BV[j], acc[i][(NH) * 2 + j], 0, 0, 0);

#define TILE64_2(BUF, T, DO2, VB)                                                       \
    do {                                                                                \
        const unsigned short* pA = lds + (BUF) * 4096 + wm * 1024 + r16 * 64;           \
        const unsigned short* pB = lds + 8192 + (BUF) * 16384 + wn * 1024 + r16 * 64;   \
        short8 a0[2], a1[2], b00[2], b01[2], b10[2], b11[2];                            \
        /* phA: read everything; 16 MFMA (n-half 0) */                                  \
        _Pragma("unroll") for (int i = 0; i < 2; ++i) {                                 \
            a0[i] = *(const short8*)(pA + i * 2048 + c0 * 8);                           \
            a1[i] = *(const short8*)(pA + i * 2048 + c1 * 8);                           \
        }                                                                               \
        _Pragma("unroll") for (int j = 0; j < 2; ++j) {                                 \
            b00[j] = *(const short8*)(pB + j * 4096 + c0 * 8);                          \
            b01[j] = *(const short8*)(pB + j * 4096 + c1 * 8);                          \
            b10[j] = *(const short8*)(pB + 8192 + j * 4096 + c0 * 8);                   \
            b11[j] = *(const short8*)(pB + 8192 + j * 4096 + c1 * 8);                   \
        }                                                                               \
        __builtin_amdgcn_s_setprio(1); MMQ4(0, a0, b00); MMQ4(0, a1, b01);              \
        __builtin_amdgcn_s_setprio(0); PBAR();                                          \
        /* phB: stage tile T+2 (consumed phA, 1 bar ago); VMC; 16 MFMA (n-half 1) */    \
        if (DO2) {                                                                      \
            ST_B4((BUF), 0, 0, (T) + 2); ST_B4((BUF), 0, 1, (T) + 2);                   \
            ST_B4((BUF), 1, 0, (T) + 2); ST_B4((BUF), 1, 1, (T) + 2);                   \
            ST_A4((BUF), (T) + 2);                                                      \
        }                                                                               \
        VMCX(VB);                                                                       \
        __builtin_amdgcn_s_setprio(1); MMQ4(1, a0, b10); MMQ4(1, a1, b11);              \
        __builtin_amdgcn_s_setprio(0);                                                  \
    } while (0)

__global__ __launch_bounds__(512, 2) void gemm8_kernel(const unsigned short* __restrict__ Acat,
                                                       const unsigned short* __restrict__ Bt,
                                                       float* __restrict__ C) {
    __shared__ unsigned short lds[65536];   // 128 KiB

    int wg  = blockIdx.x;
    int tid = threadIdx.x;
    int l   = tid & 63;
    int w   = tid >> 6;          // wave 0..7
    int wm  = w >> 2;            // 0..1
    int wn  = w & 3;             // 0..3
    int r16 = l & 15, kq = l >> 4, x = l & 7;
    int c0  = kq ^ x;            // swizzled chunk, k-step 0
    int c1  = (4 + kq) ^ x;      // swizzled chunk, k-step 1
    int srow = tid >> 3;
    int sq   = (tid & 7) ^ (srow & 7);

    if (wg < 768) {
        // ---------- full 256x256 tile ----------
        int swz = (wg & 7) * 102 + (wg >> 3);
        int mt  = swz >> 3, nt = swz & 7;
        int m0  = mt * 256, n0 = nt * 256;

        const unsigned short* aSt = Acat + (long)(m0 + srow) * K_DIM + sq * 8;
        const unsigned short* bSt = Bt   + (long)(n0 + srow) * K_DIM + sq * 8;

        f32x4 acc[8][4] = {};

        // prologue: tile0 full (8) + tile1 A-h0,B-h0,B-h1 (6); VMC(6) = tile0 done
        ST_A(0, 0, 0, 0); ST_A(0, 0, 1, 0); ST_A(0, 1, 0, 0); ST_A(0, 1, 1, 0);
        ST_B(0, 0, 0, 0); ST_B(0, 0, 1, 0); ST_B(0, 1, 0, 0); ST_B(0, 1, 1, 0);
        ST_A(1, 0, 0, 1); ST_A(1, 0, 1, 1);
        ST_B(1, 0, 0, 1); ST_B(1, 0, 1, 1); ST_B(1, 1, 0, 1); ST_B(1, 1, 1, 1);
        VMC(6); PBAR();

#pragma unroll 1
        for (int t = 0; t < 30; t += 2) {
            TILE2(0, t, 1, 1, 8, 8);     PBAR();
            TILE2(1, t + 1, 1, 1, 8, 8); PBAR();
        }
        TILE2(0, 30, 1, 0, 8, 2); PBAR();
        TILE2(1, 31, 0, 0, 0, 0);

        int orow = m0 + wm * 16 + (l >> 4) * 4;
        int ocol = n0 + wn * 16 + (l & 15);
#pragma unroll
        for (int i = 0; i < 8; ++i)
#pragma unroll
            for (int j = 0; j < 4; ++j)
#pragma unroll
                for (int q = 0; q < 4; ++q)
                    C[(long)(orow + i * 32 + q) * N_DIM + (ocol + j * 64)] = acc[i][j][q];
    } else {
        // ---------- 64x256 quarter-tile (tail M-split x4) ----------
        int k    = wg - 768;                 // 0..191
        int o    = 768 + (k >> 2);           // original tile id 768..815
        int qh   = k & 3;
        int swz  = (o & 7) * 102 + (o >> 3);
        int mt   = swz >> 3, nt = swz & 7;
        int m0   = mt * 256 + qh * 64, n0 = nt * 256;

        const unsigned short* aSt = Acat + (long)(m0 + srow) * K_DIM + sq * 8;
        const unsigned short* bSt = Bt   + (long)(n0 + srow) * K_DIM + sq * 8;

        f32x4 acc[2][4] = {};

        // prologue: T0 (5) + T1 (5); VMC(5) -> T0 complete
        ST_A4(0, 0);
        ST_B4(0, 0, 0, 0); ST_B4(0, 0, 1, 0); ST_B4(0, 1, 0, 0); ST_B4(0, 1, 1, 0);
        ST_A4(1, 1);
        ST_B4(1, 0, 0, 1); ST_B4(1, 0, 1, 1); ST_B4(1, 1, 0, 1); ST_B4(1, 1, 1, 1);
        VMC(5); PBAR();

#pragma unroll 1
        for (int t = 0; t < 30; ++t) {
            TILE64_2(t & 1, t, 1, 5); PBAR();
        }
        TILE64_2(0, 30, 0, 0); PBAR();
        TILE64_2(1, 31, 0, 0);

        int orow = m0 + wm * 16 + (l >> 4) * 4;
        int ocol = n0 + wn * 16 + (l & 15);
#pragma unroll
        for (int i = 0; i < 2; ++i)
#pragma unroll
            for (int j = 0; j < 4; ++j)
#pragma unroll
                for (int q = 0; q < 4; ++q)
                    C[(long)(orow + i * 32 + q) * N_DIM + (ocol + j * 64)] = acc[i][j][q];
    }
}

// ---------- fallback: correct (slow) fp32 tiled GEMM, used only if ws too small ----------
__global__ void naive_gemm_kernel(const float* __restrict__ A, const float* __restrict__ B,
                                  float* __restrict__ C, int M) {
    __shared__ float As[16][16];
    __shared__ float Bs[16][17];
    int tx = threadIdx.x, ty = threadIdx.y;
    int row = blockIdx.y * 16 + ty;
    int col = blockIdx.x * 16 + tx;
    float s = 0.f;
    for (int k0 = 0; k0 < K_DIM; k0 += 16) {
        As[ty][tx] = A[(long)row * K_DIM + k0 + tx];
        Bs[ty][tx] = B[(long)(k0 + ty) * N_DIM + col];
        __syncthreads();
#pragma unroll
        for (int t = 0; t < 16; ++t) s += As[ty][t] * Bs[t][tx];
        __syncthreads();
    }
    C[(long)row * N_DIM + col] = s;
}

// ---------- host launcher ----------
extern "C" void kernel_launch(void* const* d_in, const int* in_sizes, int n_in,
                              void* d_out, int out_size, void* d_ws, size_t ws_size,
                              hipStream_t stream) {
    static const int g_m[N_GROUPS]   = {4096, 2048, 1024, 8192, 512, 3072, 6144, 1024};
    static const int g_off[N_GROUPS] = {0, 4096, 6144, 7168, 15360, 15872, 18944, 25088};

    float* C = (float*)d_out;
    const size_t need = ((size_t)M_TOTAL * K_DIM + (size_t)N_DIM * K_DIM) * 2;

    if (ws_size >= need) {
        unsigned short* Acat = (unsigned short*)d_ws;
        unsigned short* Bt   = Acat + (size_t)M_TOTAL * K_DIM;

        cvt_all<<<4096 + M_TOTAL / 16, 256, 0, stream>>>(
            (const float*)d_in[0], (const float*)d_in[1], (const float*)d_in[2],
            (const float*)d_in[3], (const float*)d_in[4], (const float*)d_in[5],
            (const float*)d_in[6], (const float*)d_in[7], (const float*)d_in[8],
            Acat, Bt);

        gemm8_kernel<<<768 + 192, 512, 0, stream>>>(Acat, Bt, C);
    } else {
        for (int g = 0; g < N_GROUPS; ++g)
            naive_gemm_kernel<<<dim3(N_DIM / 16, g_m[g] / 16), dim3(16, 16), 0, stream>>>(
                (const float*)d_in[g], (const float*)d_in[8], C + (size_t)g_off[g] * N_DIM,
                g_m[g]);
    }
}

// Round 15
// 275.743 us; speedup vs baseline: 1.0085x; 1.0085x over previous
//
#include <hip/hip_runtime.h>
#include <hip/hip_bf16.h>

// ---------- types ----------
using short8  = __attribute__((ext_vector_type(8))) short;
using ushort8 = __attribute__((ext_vector_type(8))) unsigned short;
using f32x4   = __attribute__((ext_vector_type(4))) float;

#define GLB(p)  ((const __attribute__((address_space(1))) void*)(p))
#define LDSP(p) ((__attribute__((address_space(3))) void*)(p))

static __device__ __forceinline__ unsigned short f2bf(float f) {
    union { float f; unsigned u; } v; v.f = f;
    unsigned u = v.u;
    u += 0x7fffu + ((u >> 16) & 1u);   // round-to-nearest-even
    return (unsigned short)(u >> 16);
}

// ---------- problem constants ----------
#define K_DIM 2048
#define N_DIM 2048
#define M_TOTAL 26112
#define N_GROUPS 8

// ---------- kernel 1: merged convert, one launch ----------
// blocks 0..4095: B [K][N] fp32 -> Bt [N][K] bf16 (32x32 transpose tiles)
// blocks 4096..5727: A groups fp32 -> contiguous bf16 Acat (16 rows/block)
__global__ __launch_bounds__(256) void cvt_all(
        const float* __restrict__ A0, const float* __restrict__ A1,
        const float* __restrict__ A2, const float* __restrict__ A3,
        const float* __restrict__ A4, const float* __restrict__ A5,
        const float* __restrict__ A6, const float* __restrict__ A7,
        const float* __restrict__ B,
        unsigned short* __restrict__ Acat, unsigned short* __restrict__ Bt) {
    int b   = blockIdx.x;
    int tid = threadIdx.x;
    if (b < 4096) {
        __shared__ float t[32][33];
        int bx = b & 63, by = b >> 6;
        int tx = tid & 31, ty = tid >> 5;   // 32 x 8
#pragma unroll
        for (int i = 0; i < 32; i += 8)
            t[ty + i][tx] = B[(long)(by * 32 + ty + i) * N_DIM + bx * 32 + tx];
        __syncthreads();
#pragma unroll
        for (int i = 0; i < 32; i += 8)
            Bt[(long)(bx * 32 + ty + i) * K_DIM + by * 32 + tx] = f2bf(t[tx][ty + i]);
    } else {
        int ab = b - 4096;
        const float* src; int gb;   // group base (16-row units)
        if      (ab < 256)  { src = A0; gb = 0;    }
        else if (ab < 384)  { src = A1; gb = 256;  }
        else if (ab < 448)  { src = A2; gb = 384;  }
        else if (ab < 960)  { src = A3; gb = 448;  }
        else if (ab < 992)  { src = A4; gb = 960;  }
        else if (ab < 1184) { src = A5; gb = 992;  }
        else if (ab < 1568) { src = A6; gb = 1184; }
        else                { src = A7; gb = 1568; }
        const float* s    = src  + (long)(ab - gb) * 16 * K_DIM;
        unsigned short* d = Acat + (long)ab * 16 * K_DIM;
#pragma unroll 4
        for (int i = 0; i < 16; ++i) {
            long off = (long)i * K_DIM + tid * 8;
            float4 x = *(const float4*)(s + off);
            float4 y = *(const float4*)(s + off + 4);
            ushort8 o;
            o[0] = f2bf(x.x); o[1] = f2bf(x.y); o[2] = f2bf(x.z); o[3] = f2bf(x.w);
            o[4] = f2bf(y.x); o[5] = f2bf(y.y); o[6] = f2bf(y.z); o[7] = f2bf(y.w);
            *(ushort8*)(d + off) = o;
        }
    }
}

// ---------- kernel 2: 256x256 GEMM, barrier-thinned (4 barriers/tile) ----------
// Only post-MFMA barriers carry region safety: a stage into region R occurs >=1
// all-waves barrier after R's consumption.  Tile-end VMC hoisted into ph4 after
// its stages (drains the same 8-oldest = tile T+1's loads; overlaps ph4's MFMAs).

#define PBAR() __builtin_amdgcn_s_barrier()
#define VMC(n)  asm volatile("s_waitcnt vmcnt(" #n ")" ::: "memory")

#define ST_A(BUF, H, L, TT)                                                        \
    __builtin_amdgcn_global_load_lds(                                              \
        GLB(aSt + (long)((H) * 128 + (L) * 64) * K_DIM + (TT) * 64),               \
        LDSP(lds + (BUF) * 32768 + (H) * 8192 + (L) * 4096 + w * 512), 16, 0, 0)
#define ST_B(BUF, H, L, TT)                                                        \
    __builtin_amdgcn_global_load_lds(                                              \
        GLB(bSt + (long)((H) * 128 + (L) * 64) * K_DIM + (TT) * 64),               \
        LDSP(lds + (BUF) * 32768 + 16384 + (H) * 8192 + (L) * 4096 + w * 512), 16, 0, 0)

#define MMQ(MH, NH, AV, BV)                                                        \
    _Pragma("unroll") for (int i = 0; i < 4; ++i)                                  \
    _Pragma("unroll") for (int j = 0; j < 2; ++j)                                  \
        acc[(MH) * 4 + i][(NH) * 2 + j] = __builtin_amdgcn_mfma_f32_16x16x32_bf16( \
            AV[i], BV[j], acc[(MH) * 4 + i][(NH) * 2 + j], 0, 0, 0);

// ledger (steady, DO1=DO2=1): entering tile = 6 outstanding (T+2 partial);
// ph1 +2 (A(T+1)h1), ph2 +2, ph3 +2, ph4 +2 -> 14; VMC(6) in ph4 drains the
// 8 oldest = ALL of tile T+1's loads, keeps 6 = tile T+2's.
#define TILE(BUF, T, DO1, DO2)                                                          \
    do {                                                                                \
        const unsigned short* pA = lds + (BUF) * 32768 + wm * 1024 + r16 * 64;          \
        const unsigned short* pB = lds + (BUF) * 32768 + 16384 + wn * 1024 + r16 * 64;  \
        short8 a0[4], a1[4], b00[2], b01[2], b10[2], b11[2];                            \
        /* ph1: read A-h0 + B-h0; stage A(T+1)-h1 -> buf^1; MFMA m0n0 (no pre-bar) */   \
        _Pragma("unroll") for (int i = 0; i < 4; ++i) {                                 \
            a0[i] = *(const short8*)(pA + i * 2048 + c0 * 8);                           \
            a1[i] = *(const short8*)(pA + i * 2048 + c1 * 8);                           \
        }                                                                               \
        _Pragma("unroll") for (int j = 0; j < 2; ++j) {                                 \
            b00[j] = *(const short8*)(pB + j * 4096 + c0 * 8);                          \
            b01[j] = *(const short8*)(pB + j * 4096 + c1 * 8);                          \
        }                                                                               \
        if (DO1) { ST_A((BUF) ^ 1, 1, 0, (T) + 1); ST_A((BUF) ^ 1, 1, 1, (T) + 1); }    \
        __builtin_amdgcn_s_setprio(1); MMQ(0, 0, a0, b00); MMQ(0, 0, a1, b01);          \
        __builtin_amdgcn_s_setprio(0); PBAR();                                          \
        /* ph2: read B-h1; stage A(T+2)-h0 -> buf (A-h0 consumed ph1, 1 bar ago) */     \
        _Pragma("unroll") for (int j = 0; j < 2; ++j) {                                 \
            b10[j] = *(const short8*)(pB + 8192 + j * 4096 + c0 * 8);                   \
            b11[j] = *(const short8*)(pB + 8192 + j * 4096 + c1 * 8);                   \
        }                                                                               \
        if (DO2) { ST_A((BUF), 0, 0, (T) + 2); ST_A((BUF), 0, 1, (T) + 2); }            \
        __builtin_amdgcn_s_setprio(1); MMQ(0, 1, a0, b10); MMQ(0, 1, a1, b11);          \
        __builtin_amdgcn_s_setprio(0); PBAR();                                          \
        /* ph3: read A-h1; stage B(T+2)-h0 -> buf (B-h0 consumed ph1) */                \
        _Pragma("unroll") for (int i = 0; i < 4; ++i) {                                 \
            a0[i] = *(const short8*)(pA + 8192 + i * 2048 + c0 * 8);                    \
            a1[i] = *(const short8*)(pA + 8192 + i * 2048 + c1 * 8);                    \
        }                                                                               \
        if (DO2) { ST_B((BUF), 0, 0, (T) + 2); ST_B((BUF), 0, 1, (T) + 2); }            \
        __builtin_amdgcn_s_setprio(1); MMQ(1, 0, a0, b00); MMQ(1, 0, a1, b01);          \
        __builtin_amdgcn_s_setprio(0); PBAR();                                          \
        /* ph4: stage B(T+2)-h1 (B-h1 consumed ph2); hoisted VMC(6); MFMA m1n1 */       \
        if (DO2) { ST_B((BUF), 1, 0, (T) + 2); ST_B((BUF), 1, 1, (T) + 2); VMC(6); }    \
        __builtin_amdgcn_s_setprio(1); MMQ(1, 1, a0, b10); MMQ(1, 1, a1, b11);          \
        __builtin_amdgcn_s_setprio(0);                                                  \
    } while (0)

// ---- 64-row quarter tile (tail), same thinning; 5 loads/tile, VMC(5) hoisted ----
#define ST_A4(BUF, TT)                                                             \
    __builtin_amdgcn_global_load_lds(                                              \
        GLB(aSt + (long)(TT) * 64),                                                \
        LDSP(lds + (BUF) * 4096 + w * 512), 16, 0, 0)
#define ST_B4(BUF, H, L, TT)                                                       \
    __builtin_amdgcn_global_load_lds(                                              \
        GLB(bSt + (long)((H) * 128 + (L) * 64) * K_DIM + (TT) * 64),               \
        LDSP(lds + 8192 + (BUF) * 16384 + (H) * 8192 + (L) * 4096 + w * 512), 16, 0, 0)

#define MMQ4(NH, AV, BV)                                                           \
    _Pragma("unroll") for (int i = 0; i < 2; ++i)                                  \
    _Pragma("unroll") for (int j = 0; j < 2; ++j)                                  \
        acc[i][(NH) * 2 + j] = __builtin_amdgcn_mfma_f32_16x16x32_bf16(            \
            AV[i], BV[j], acc[i][(NH) * 2 + j], 0, 0, 0);

#define TILE64(BUF, T, DO2)                                                             \
    do {                                                                                \
        const unsigned short* pA = lds + (BUF) * 4096 + wm * 1024 + r16 * 64;           \
        const unsigned short* pB = lds + 8192 + (BUF) * 16384 + wn * 1024 + r16 * 64;   \
        short8 a0[2], a1[2], b00[2], b01[2], b10[2], b11[2];                            \
        /* ph1: read A (all) + B-h0; MFMA (no pre-bar) */                               \
        _Pragma("unroll") for (int i = 0; i < 2; ++i) {                                 \
            a0[i] = *(const short8*)(pA + i * 2048 + c0 * 8);                           \
            a1[i] = *(const short8*)(pA + i * 2048 + c1 * 8);                           \
        }                                                                               \
        _Pragma("unroll") for (int j = 0; j < 2; ++j) {                                 \
            b00[j] = *(const short8*)(pB + j * 4096 + c0 * 8);                          \
            b01[j] = *(const short8*)(pB + j * 4096 + c1 * 8);                          \
        }                                                                               \
        __builtin_amdgcn_s_setprio(1); MMQ4(0, a0, b00);                                \
        __builtin_amdgcn_s_setprio(0); PBAR();                                          \
        /* ph2: read B-h1; MFMA */                                                      \
        _Pragma("unroll") for (int j = 0; j < 2; ++j) {                                 \
            b10[j] = *(const short8*)(pB + 8192 + j * 4096 + c0 * 8);                   \
            b11[j] = *(const short8*)(pB + 8192 + j * 4096 + c1 * 8);                   \
        }                                                                               \
        __builtin_amdgcn_s_setprio(1); MMQ4(0, a1, b01);                                \
        __builtin_amdgcn_s_setprio(0); PBAR();                                          \
        /* ph3: stage B(T+2)-h0 (consumed ph1); MFMA */                                 \
        if (DO2) { ST_B4((BUF), 0, 0, (T) + 2); ST_B4((BUF), 0, 1, (T) + 2); }          \
        __builtin_amdgcn_s_setprio(1); MMQ4(1, a0, b10);                                \
        __builtin_amdgcn_s_setprio(0); PBAR();                                          \
        /* ph4: stage B(T+2)-h1 + A(T+2) (consumed ph2/ph1); hoisted VMC(5); MFMA */    \
        if (DO2) { ST_B4((BUF), 1, 0, (T) + 2); ST_B4((BUF), 1, 1, (T) + 2);            \
                   ST_A4((BUF), (T) + 2); VMC(5); }                                     \
        __builtin_amdgcn_s_setprio(1); MMQ4(1, a1, b11);                                \
        __builtin_amdgcn_s_setprio(0);                                                  \
    } while (0)

__global__ __launch_bounds__(512, 2) void gemm8_kernel(const unsigned short* __restrict__ Acat,
                                                       const unsigned short* __restrict__ Bt,
                                                       float* __restrict__ C) {
    __shared__ unsigned short lds[65536];   // 128 KiB

    int wg  = blockIdx.x;
    int tid = threadIdx.x;
    int l   = tid & 63;
    int w   = tid >> 6;          // wave 0..7
    int wm  = w >> 2;            // 0..1
    int wn  = w & 3;             // 0..3
    int r16 = l & 15, kq = l >> 4, x = l & 7;
    int c0  = kq ^ x;            // swizzled chunk, k-step 0
    int c1  = (4 + kq) ^ x;      // swizzled chunk, k-step 1
    int srow = tid >> 3;
    int sq   = (tid & 7) ^ (srow & 7);

    if (wg < 768) {
        // ---------- full 256x256 tile ----------
        int swz = (wg & 7) * 102 + (wg >> 3);
        int mt  = swz >> 3, nt = swz & 7;
        int m0  = mt * 256, n0 = nt * 256;

        const unsigned short* aSt = Acat + (long)(m0 + srow) * K_DIM + sq * 8;
        const unsigned short* bSt = Bt   + (long)(n0 + srow) * K_DIM + sq * 8;

        f32x4 acc[8][4] = {};

        ST_A(0, 0, 0, 0); ST_A(0, 0, 1, 0); ST_A(0, 1, 0, 0); ST_A(0, 1, 1, 0);
        ST_B(0, 0, 0, 0); ST_B(0, 0, 1, 0); ST_B(0, 1, 0, 0); ST_B(0, 1, 1, 0);
        ST_A(1, 0, 0, 1); ST_A(1, 0, 1, 1);
        ST_B(1, 0, 0, 1); ST_B(1, 0, 1, 1); ST_B(1, 1, 0, 1); ST_B(1, 1, 1, 1);
        VMC(6); PBAR();

#pragma unroll 1
        for (int t = 0; t < 30; t += 2) {
            TILE(0, t, 1, 1);     PBAR();
            TILE(1, t + 1, 1, 1); PBAR();
        }
        TILE(0, 30, 1, 0); VMC(0); PBAR();
        TILE(1, 31, 0, 0);

        int orow = m0 + wm * 16 + (l >> 4) * 4;
        int ocol = n0 + wn * 16 + (l & 15);
#pragma unroll
        for (int i = 0; i < 8; ++i)
#pragma unroll
            for (int j = 0; j < 4; ++j)
#pragma unroll
                for (int q = 0; q < 4; ++q)
                    C[(long)(orow + i * 32 + q) * N_DIM + (ocol + j * 64)] = acc[i][j][q];
    } else {
        // ---------- 64x256 quarter-tile (tail M-split x4) ----------
        int k    = wg - 768;                 // 0..191
        int o    = 768 + (k >> 2);           // original tile id 768..815
        int qh   = k & 3;
        int swz  = (o & 7) * 102 + (o >> 3);
        int mt   = swz >> 3, nt = swz & 7;
        int m0   = mt * 256 + qh * 64, n0 = nt * 256;

        const unsigned short* aSt = Acat + (long)(m0 + srow) * K_DIM + sq * 8;
        const unsigned short* bSt = Bt   + (long)(n0 + srow) * K_DIM + sq * 8;

        f32x4 acc[2][4] = {};

        ST_A4(0, 0);
        ST_B4(0, 0, 0, 0); ST_B4(0, 0, 1, 0); ST_B4(0, 1, 0, 0); ST_B4(0, 1, 1, 0);
        ST_A4(1, 1);
        ST_B4(1, 0, 0, 1); ST_B4(1, 0, 1, 1); ST_B4(1, 1, 0, 1); ST_B4(1, 1, 1, 1);
        VMC(5); PBAR();

#pragma unroll 1
        for (int t = 0; t < 30; ++t) {
            TILE64(t & 1, t, 1); PBAR();
        }
        TILE64(0, 30, 0); VMC(0); PBAR();
        TILE64(1, 31, 0);

        int orow = m0 + wm * 16 + (l >> 4) * 4;
        int ocol = n0 + wn * 16 + (l & 15);
#pragma unroll
        for (int i = 0; i < 2; ++i)
#pragma unroll
            for (int j = 0; j < 4; ++j)
#pragma unroll
                for (int q = 0; q < 4; ++q)
                    C[(long)(orow + i * 32 + q) * N_DIM + (ocol + j * 64)] = acc[i][j][q];
    }
}

// ---------- fallback: correct (slow) fp32 tiled GEMM, used only if ws too small ----------
__global__ void naive_gemm_kernel(const float* __restrict__ A, const float* __restrict__ B,
                                  float* __restrict__ C, int M) {
    __shared__ float As[16][16];
    __shared__ float Bs[16][17];
    int tx = threadIdx.x, ty = threadIdx.y;
    int row = blockIdx.y * 16 + ty;
    int col = blockIdx.x * 16 + tx;
    float s = 0.f;
    for (int k0 = 0; k0 < K_DIM; k0 += 16) {
        As[ty][tx] = A[(long)row * K_DIM + k0 + tx];
        Bs[ty][tx] = B[(long)(k0 + ty) * N_DIM + col];
        __syncthreads();
#pragma unroll
        for (int t = 0; t < 16; ++t) s += As[ty][t] * Bs[t][tx];
        __syncthreads();
    }
    C[(long)row * N_DIM + col] = s;
}

// ---------- host launcher ----------
extern "C" void kernel_launch(void* const* d_in, const int* in_sizes, int n_in,
                              void* d_out, int out_size, void* d_ws, size_t ws_size,
                              hipStream_t stream) {
    static const int g_m[N_GROUPS]   = {4096, 2048, 1024, 8192, 512, 3072, 6144, 1024};
    static const int g_off[N_GROUPS] = {0, 4096, 6144, 7168, 15360, 15872, 18944, 25088};

    float* C = (float*)d_out;
    const size_t need = ((size_t)M_TOTAL * K_DIM + (size_t)N_DIM * K_DIM) * 2;

    if (ws_size >= need) {
        unsigned short* Acat = (unsigned short*)d_ws;
        unsigned short* Bt   = Acat + (size_t)M_TOTAL * K_DIM;

        cvt_all<<<4096 + M_TOTAL / 16, 256, 0, stream>>>(
            (const float*)d_in[0], (const float*)d_in[1], (const float*)d_in[2],
            (const float*)d_in[3], (const float*)d_in[4], (const float*)d_in[5],
            (const float*)d_in[6], (const float*)d_in[7], (const float*)d_in[8],
            Acat, Bt);

        gemm8_kernel<<<768 + 192, 512, 0, stream>>>(Acat, Bt, C);
    } else {
        for (int g = 0; g < N_GROUPS; ++g)
            naive_gemm_kernel<<<dim3(N_DIM / 16, g_m[g] / 16), dim3(16, 16), 0, stream>>>(
                (const float*)d_in[g], (const float*)d_in[8], C + (size_t)g_off[g] * N_DIM,
                g_m[g]);
    }
}